// Round 5
// baseline (150.872 us; speedup 1.0000x reference)
//
#include <hip/hip_runtime.h>

// CINLayer: cin_out[b,f,d] = sum_{c,n} W[f,c,n] * xj[b,c,d] * x0[b,n,d]
//           cin_p_out[b,f] = sum_d cin_out[b,f,d]
// B=2048, C=64, N=64, D=64, F=128.
//
// R5: barrier-free, LDS-free main loop. Wave = 2 batches x 32 f (mf=4,nf=1);
// each wave streams its own 4KB/c W-fragment slice L2->registers (fragment-
// major Wb: 16B/lane contiguous). Named even/odd register double-buffers
// (no runtime indexing -> no scratch, rule #20). x0 A-frags hoisted once via
// a 16KB LDS transpose. setprio(1) around MFMA cluster. No main-loop LDS ops.

typedef _Float16 f16;
typedef __attribute__((ext_vector_type(8))) _Float16 half8;
typedef __attribute__((ext_vector_type(16))) float f32x16;
typedef __attribute__((ext_vector_type(4))) float f32x4;

#define MFMA(a, b, c) __builtin_amdgcn_mfma_f32_32x32x16_f16(a, b, c, 0, 0, 0)

// ---- pre-pass: scatter W f32 -> f16 fragment-major ----
// Wb slot layout: [c][slot][8], slot = (g*4+kk)*64 + hi*32 + lr
//   holds W[f=g*32+lr][c][kk*16+hi*8 .. +8]
__global__ __launch_bounds__(256) void wscat_kernel(const float* __restrict__ W,
                                                    f16* __restrict__ Wb) {
  const int tid = blockIdx.x * 256 + threadIdx.x;   // 65536 threads
  const int c = tid >> 10, s = tid & 1023;
  const int gk = s >> 6, ln = s & 63;
  const int g = gk >> 2, kk = gk & 3, hi = ln >> 5, lr = ln & 31;
  const int f = g * 32 + lr, n0 = kk * 16 + hi * 8;
  const float* src = W + (size_t)f * 4096 + c * 64 + n0;
  const float4 a = *(const float4*)src;
  const float4 b = *(const float4*)(src + 4);
  half8 r;
  r[0] = (f16)a.x; r[1] = (f16)a.y; r[2] = (f16)a.z; r[3] = (f16)a.w;
  r[4] = (f16)b.x; r[5] = (f16)b.y; r[6] = (f16)b.z; r[7] = (f16)b.w;
  *(half8*)(Wb + (size_t)c * 8192 + s * 8) = r;
}

__global__ __launch_bounds__(256, 2) void cin_kernel(
    const float* __restrict__ xj, const float* __restrict__ x0,
    const f16* __restrict__ Wb, float* __restrict__ out,
    float* __restrict__ pout) {
  // x0T[bb*4096 + d*64 + ((n>>3)^(d&7))*8 + (n&7)] = f16(x0[b0+bb][n][d])
  __shared__ f16 x0T[2 * 4096];   // 16 KB (one-time transpose staging only)

  const int t = threadIdx.x;
  const int wid = t >> 6, lane = t & 63;
  const int b0 = blockIdx.x * 2;

  // ---- one-time: transpose-stage x0 as f16 (chunk-swizzled) ----
#pragma unroll
  for (int bb = 0; bb < 2; ++bb) {
    const float* s0 = x0 + (size_t)(b0 + bb) * 4096;
    const int n = lane, d0 = wid * 16;
    const int chb = n >> 3, sub = n & 7;
#pragma unroll
    for (int q = 0; q < 4; ++q) {
      const float4 v = *(const float4*)(s0 + n * 64 + d0 + q * 4);
#pragma unroll
      for (int j = 0; j < 4; ++j) {
        const int d = d0 + q * 4 + j;
        x0T[bb * 4096 + d * 64 + ((chb ^ (d & 7)) << 3) + sub] =
            (f16)(((const float*)&v)[j]);
      }
    }
  }
  __syncthreads();

  const int wg = wid;                       // f-group: f = wg*32 + lr
  const int lr = lane & 31, hi = lane >> 5;

  // ---- hoisted x0 A-fragments: af[mf][kk], mf = (bb<<1)|dh ----
  half8 af[4][4];
#pragma unroll
  for (int mf = 0; mf < 4; ++mf) {
    const int bb = mf >> 1;
    const int d = (mf & 1) * 32 + lr;
#pragma unroll
    for (int kk = 0; kk < 4; ++kk)
      af[mf][kk] = *(const half8*)&x0T[bb * 4096 + d * 64 +
                                       (((kk * 2 + hi) ^ (d & 7)) << 3)];
  }

  f32x16 acc[4] = {};

  // W stream: wave wg's slice, 16B/lane contiguous per (c,kk)
  const half8* wp = (const half8*)Wb + wg * 256 + lane;   // + c*1024 + kk*64
  // xj: mf offsets {0, 32, 4096, 4128} + c*64
  const float* xjp = xj + (size_t)b0 * 4096 + lr;

  // ---- prologue: c=0 -> A sets, c=1 -> B sets ----
  half8 wA0 = wp[0],        wA1 = wp[64],        wA2 = wp[128],        wA3 = wp[192];
  half8 wB0 = wp[1024],     wB1 = wp[1024 + 64], wB2 = wp[1024 + 128], wB3 = wp[1024 + 192];
  float xA0 = xjp[0],   xA1 = xjp[32],   xA2 = xjp[4096],      xA3 = xjp[4128];
  float xB0 = xjp[64],  xB1 = xjp[96],   xB2 = xjp[4096 + 64], xB3 = xjp[4096 + 96];

#pragma unroll 1
  for (int cc = 0; cc < 32; ++cc) {
    // ================= even c = 2*cc (A sets) =================
    {
      const f16 h0 = (f16)xA0, h1 = (f16)xA1, h2 = (f16)xA2, h3 = (f16)xA3;
      const int cn = (2 * cc + 2 < 64) ? 2 * cc + 2 : 63;
      __builtin_amdgcn_s_setprio(1);
#pragma unroll
      for (int kk = 0; kk < 4; ++kk) {
        const half8 w = (kk == 0) ? wA0 : (kk == 1) ? wA1 : (kk == 2) ? wA2 : wA3;
        acc[0] = MFMA(af[0][kk] * h0, w, acc[0]);
        acc[1] = MFMA(af[1][kk] * h1, w, acc[1]);
        acc[2] = MFMA(af[2][kk] * h2, w, acc[2]);
        acc[3] = MFMA(af[3][kk] * h3, w, acc[3]);
      }
      __builtin_amdgcn_s_setprio(0);
      wA0 = wp[cn * 1024];       wA1 = wp[cn * 1024 + 64];
      wA2 = wp[cn * 1024 + 128]; wA3 = wp[cn * 1024 + 192];
      xA0 = xjp[cn * 64];        xA1 = xjp[cn * 64 + 32];
      xA2 = xjp[cn * 64 + 4096]; xA3 = xjp[cn * 64 + 4128];
    }
    // ================= odd c = 2*cc+1 (B sets) =================
    {
      const f16 h0 = (f16)xB0, h1 = (f16)xB1, h2 = (f16)xB2, h3 = (f16)xB3;
      const int cn = (2 * cc + 3 < 64) ? 2 * cc + 3 : 63;
      __builtin_amdgcn_s_setprio(1);
#pragma unroll
      for (int kk = 0; kk < 4; ++kk) {
        const half8 w = (kk == 0) ? wB0 : (kk == 1) ? wB1 : (kk == 2) ? wB2 : wB3;
        acc[0] = MFMA(af[0][kk] * h0, w, acc[0]);
        acc[1] = MFMA(af[1][kk] * h1, w, acc[1]);
        acc[2] = MFMA(af[2][kk] * h2, w, acc[2]);
        acc[3] = MFMA(af[3][kk] * h3, w, acc[3]);
      }
      __builtin_amdgcn_s_setprio(0);
      wB0 = wp[cn * 1024];       wB1 = wp[cn * 1024 + 64];
      wB2 = wp[cn * 1024 + 128]; wB3 = wp[cn * 1024 + 192];
      xB0 = xjp[cn * 64];        xB1 = xjp[cn * 64 + 32];
      xB2 = xjp[cn * 64 + 4096]; xB3 = xjp[cn * 64 + 4128];
    }
  }

  // ---- epilogue: D layout col=lane&31 (f), row=(reg&3)+8*(reg>>2)+4*hi (d) ----
  const int fcol = wg * 32 + lr;
  float ps[4];
#pragma unroll
  for (int mf = 0; mf < 4; ++mf) {
    const int b = b0 + (mf >> 1);
    float* ob = out + (size_t)b * 8192 + (size_t)fcol * 64 + (mf & 1) * 32;
    const f32x16 v = acc[mf];
    float s = 0.f;
#pragma unroll
    for (int q = 0; q < 4; ++q) {
      f32x4 vv = { v[4 * q], v[4 * q + 1], v[4 * q + 2], v[4 * q + 3] };
      *(f32x4*)(ob + q * 8 + hi * 4) = vv;
      s += vv[0] + vv[1] + vv[2] + vv[3];
    }
    ps[mf] = s;
  }
  float pA = ps[0] + ps[1];   // batch b0
  float pB = ps[2] + ps[3];   // batch b0+1
  pA += __shfl_xor(pA, 32, 64);
  pB += __shfl_xor(pB, 32, 64);
  if (hi == 0) {
    pout[(size_t)b0 * 128 + fcol] = pA;
    pout[(size_t)(b0 + 1) * 128 + fcol] = pB;
  }
}

extern "C" void kernel_launch(void* const* d_in, const int* in_sizes, int n_in,
                              void* d_out, int out_size, void* d_ws, size_t ws_size,
                              hipStream_t stream) {
  const float* xj = (const float*)d_in[0];   // (2048, 64, 64)
  const float* x0 = (const float*)d_in[1];   // (2048, 64, 64)
  const float* W  = (const float*)d_in[2];   // (128, 64, 64)
  float* out  = (float*)d_out;               // cin_out (2048,128,64), cin_p_out (2048,128)
  float* pout = out + (size_t)2048 * 128 * 64;
  f16* Wb = (f16*)d_ws;                      // 1 MiB fragment-major f16 W

  wscat_kernel<<<256, 256, 0, stream>>>(W, Wb);
  cin_kernel<<<1024, 256, 0, stream>>>(xj, x0, Wb, out, pout);
}

// Round 6
// 139.809 us; speedup vs baseline: 1.0791x; 1.0791x over previous
//
#include <hip/hip_runtime.h>

// CINLayer: cin_out[b,f,d] = sum_{c,n} W[f,c,n] * xj[b,c,d] * x0[b,n,d]
//           cin_p_out[b,f] = sum_d cin_out[b,f,d]
// B=2048, C=64, N=64, D=64, F=128.
//
// R6: R5's barrier-free reg-stream structure, but xj staged whole into LDS
// (f16) in the prologue -> main loop has ZERO global loads besides the W
// stream (L2-hot, 2-phase prefetch). xj per-c via ds_read_u16 (broadcast,
// conflict-free), prefetched one phase ahead. No per-c vmem latency.

typedef _Float16 f16;
typedef __attribute__((ext_vector_type(8))) _Float16 half8;
typedef __attribute__((ext_vector_type(16))) float f32x16;
typedef __attribute__((ext_vector_type(4))) float f32x4;

#define MFMA(a, b, c) __builtin_amdgcn_mfma_f32_32x32x16_f16(a, b, c, 0, 0, 0)

// ---- pre-pass: scatter W f32 -> f16 fragment-major ----
// Wb slot layout: [c][slot][8], slot = (g*4+kk)*64 + hi*32 + lr
//   holds W[f=g*32+lr][c][kk*16+hi*8 .. +8]
__global__ __launch_bounds__(256) void wscat_kernel(const float* __restrict__ W,
                                                    f16* __restrict__ Wb) {
  const int tid = blockIdx.x * 256 + threadIdx.x;   // 65536 threads
  const int c = tid >> 10, s = tid & 1023;
  const int gk = s >> 6, ln = s & 63;
  const int g = gk >> 2, kk = gk & 3, hi = ln >> 5, lr = ln & 31;
  const int f = g * 32 + lr, n0 = kk * 16 + hi * 8;
  const float* src = W + (size_t)f * 4096 + c * 64 + n0;
  const float4 a = *(const float4*)src;
  const float4 b = *(const float4*)(src + 4);
  half8 r;
  r[0] = (f16)a.x; r[1] = (f16)a.y; r[2] = (f16)a.z; r[3] = (f16)a.w;
  r[4] = (f16)b.x; r[5] = (f16)b.y; r[6] = (f16)b.z; r[7] = (f16)b.w;
  *(half8*)(Wb + (size_t)c * 8192 + s * 8) = r;
}

__global__ __launch_bounds__(256, 2) void cin_kernel(
    const float* __restrict__ xj, const float* __restrict__ x0,
    const f16* __restrict__ Wb, float* __restrict__ out,
    float* __restrict__ pout) {
  // x0T[bb*4096 + d*64 + ((n>>3)^(d&7))*8 + (n&7)] = f16(x0[b0+bb][n][d])
  __shared__ f16 x0T[2 * 4096];   // 16 KB
  // xjL[bb*4096 + c*64 + d] = f16(xj[b0+bb][c][d])   (linear copy)
  __shared__ f16 xjL[2 * 4096];   // 16 KB

  const int t = threadIdx.x;
  const int wid = t >> 6, lane = t & 63;
  const int b0 = blockIdx.x * 2;

  // ---- one-time: stage x0 (transposed, swizzled) + xj (linear) as f16 ----
#pragma unroll
  for (int bb = 0; bb < 2; ++bb) {
    const float* s0 = x0 + (size_t)(b0 + bb) * 4096;
    const float* sj = xj + (size_t)(b0 + bb) * 4096;
    // x0: thread reads row n=lane, d-chunk wid*16
    {
      const int n = lane, d0 = wid * 16;
      const int chb = n >> 3, sub = n & 7;
#pragma unroll
      for (int q = 0; q < 4; ++q) {
        const float4 v = *(const float4*)(s0 + n * 64 + d0 + q * 4);
#pragma unroll
        for (int j = 0; j < 4; ++j) {
          const int d = d0 + q * 4 + j;
          x0T[bb * 4096 + d * 64 + ((chb ^ (d & 7)) << 3) + sub] =
              (f16)(((const float*)&v)[j]);
        }
      }
    }
    // xj: linear f16 copy, lane-consecutive float4
#pragma unroll
    for (int p = 0; p < 4; ++p) {
      const int e = p * 1024 + t * 4;
      const float4 v = *(const float4*)(sj + e);
      f16* dst = &xjL[bb * 4096 + e];
      dst[0] = (f16)v.x; dst[1] = (f16)v.y; dst[2] = (f16)v.z; dst[3] = (f16)v.w;
    }
  }
  __syncthreads();

  const int wg = wid;                       // f-group: f = wg*32 + lr
  const int lr = lane & 31, hi = lane >> 5;

  // ---- hoisted x0 A-fragments: af[mf][kk], mf = (bb<<1)|dh ----
  half8 af[4][4];
#pragma unroll
  for (int mf = 0; mf < 4; ++mf) {
    const int bb = mf >> 1;
    const int d = (mf & 1) * 32 + lr;
#pragma unroll
    for (int kk = 0; kk < 4; ++kk)
      af[mf][kk] = *(const half8*)&x0T[bb * 4096 + d * 64 +
                                       (((kk * 2 + hi) ^ (d & 7)) << 3)];
  }

  f32x16 acc[4] = {};

  // W stream: wave wg's slice, 16B/lane contiguous per (c,kk)
  const half8* wp = (const half8*)Wb + wg * 256 + lane;   // + c*1024 + kk*64
  // xj LDS read base: lane needs xjL[bb*4096 + c*64 + dh*32 + lr]  (hi-broadcast)
  const f16* xjb = &xjL[lr];

  // ---- prologue: c=0 -> A sets, c=1 -> B sets ----
  half8 wA0 = wp[0],        wA1 = wp[64],        wA2 = wp[128],        wA3 = wp[192];
  half8 wB0 = wp[1024],     wB1 = wp[1024 + 64], wB2 = wp[1024 + 128], wB3 = wp[1024 + 192];
  f16 xA0 = xjb[0],    xA1 = xjb[32],   xA2 = xjb[4096],      xA3 = xjb[4096 + 32];
  f16 xB0 = xjb[64],   xB1 = xjb[96],   xB2 = xjb[4096 + 64], xB3 = xjb[4096 + 96];

#pragma unroll 1
  for (int cc = 0; cc < 32; ++cc) {
    // ================= even c = 2*cc (A sets) =================
    {
      const f16 h0 = xA0, h1 = xA1, h2 = xA2, h3 = xA3;
      const int cn = (2 * cc + 2 < 64) ? 2 * cc + 2 : 63;
      __builtin_amdgcn_s_setprio(1);
#pragma unroll
      for (int kk = 0; kk < 4; ++kk) {
        const half8 w = (kk == 0) ? wA0 : (kk == 1) ? wA1 : (kk == 2) ? wA2 : wA3;
        acc[0] = MFMA(af[0][kk] * h0, w, acc[0]);
        acc[1] = MFMA(af[1][kk] * h1, w, acc[1]);
        acc[2] = MFMA(af[2][kk] * h2, w, acc[2]);
        acc[3] = MFMA(af[3][kk] * h3, w, acc[3]);
      }
      __builtin_amdgcn_s_setprio(0);
      wA0 = wp[cn * 1024];       wA1 = wp[cn * 1024 + 64];
      wA2 = wp[cn * 1024 + 128]; wA3 = wp[cn * 1024 + 192];
      xA0 = xjb[cn * 64];        xA1 = xjb[cn * 64 + 32];
      xA2 = xjb[cn * 64 + 4096]; xA3 = xjb[cn * 64 + 4128];
    }
    // ================= odd c = 2*cc+1 (B sets) =================
    {
      const f16 h0 = xB0, h1 = xB1, h2 = xB2, h3 = xB3;
      const int cn = (2 * cc + 3 < 64) ? 2 * cc + 3 : 63;
      __builtin_amdgcn_s_setprio(1);
#pragma unroll
      for (int kk = 0; kk < 4; ++kk) {
        const half8 w = (kk == 0) ? wB0 : (kk == 1) ? wB1 : (kk == 2) ? wB2 : wB3;
        acc[0] = MFMA(af[0][kk] * h0, w, acc[0]);
        acc[1] = MFMA(af[1][kk] * h1, w, acc[1]);
        acc[2] = MFMA(af[2][kk] * h2, w, acc[2]);
        acc[3] = MFMA(af[3][kk] * h3, w, acc[3]);
      }
      __builtin_amdgcn_s_setprio(0);
      wB0 = wp[cn * 1024];       wB1 = wp[cn * 1024 + 64];
      wB2 = wp[cn * 1024 + 128]; wB3 = wp[cn * 1024 + 192];
      xB0 = xjb[cn * 64];        xB1 = xjb[cn * 64 + 32];
      xB2 = xjb[cn * 64 + 4096]; xB3 = xjb[cn * 64 + 4128];
    }
  }

  // ---- epilogue: D layout col=lane&31 (f), row=(reg&3)+8*(reg>>2)+4*hi (d) ----
  const int fcol = wg * 32 + lr;
  float ps[4];
#pragma unroll
  for (int mf = 0; mf < 4; ++mf) {
    const int b = b0 + (mf >> 1);
    float* ob = out + (size_t)b * 8192 + (size_t)fcol * 64 + (mf & 1) * 32;
    const f32x16 v = acc[mf];
    float s = 0.f;
#pragma unroll
    for (int q = 0; q < 4; ++q) {
      f32x4 vv = { v[4 * q], v[4 * q + 1], v[4 * q + 2], v[4 * q + 3] };
      *(f32x4*)(ob + q * 8 + hi * 4) = vv;
      s += vv[0] + vv[1] + vv[2] + vv[3];
    }
    ps[mf] = s;
  }
  float pA = ps[0] + ps[1];   // batch b0
  float pB = ps[2] + ps[3];   // batch b0+1
  pA += __shfl_xor(pA, 32, 64);
  pB += __shfl_xor(pB, 32, 64);
  if (hi == 0) {
    pout[(size_t)b0 * 128 + fcol] = pA;
    pout[(size_t)(b0 + 1) * 128 + fcol] = pB;
  }
}

extern "C" void kernel_launch(void* const* d_in, const int* in_sizes, int n_in,
                              void* d_out, int out_size, void* d_ws, size_t ws_size,
                              hipStream_t stream) {
  const float* xj = (const float*)d_in[0];   // (2048, 64, 64)
  const float* x0 = (const float*)d_in[1];   // (2048, 64, 64)
  const float* W  = (const float*)d_in[2];   // (128, 64, 64)
  float* out  = (float*)d_out;               // cin_out (2048,128,64), cin_p_out (2048,128)
  float* pout = out + (size_t)2048 * 128 * 64;
  f16* Wb = (f16*)d_ws;                      // 1 MiB fragment-major f16 W

  wscat_kernel<<<256, 256, 0, stream>>>(W, Wb);
  cin_kernel<<<1024, 256, 0, stream>>>(xj, x0, Wb, out, pout);
}

// Round 7
// 139.736 us; speedup vs baseline: 1.0797x; 1.0005x over previous
//
#include <hip/hip_runtime.h>

// CINLayer: cin_out[b,f,d] = sum_{c,n} W[f,c,n] * xj[b,c,d] * x0[b,n,d]
//           cin_p_out[b,f] = sum_d cin_out[b,f,d]
// B=2048, C=64, N=64, D=64, F=128.
//
// R7 = R6 structure + VALU squeeze:
//  - A' formed via explicit half2 vector ops -> guaranteed v_pk_mul_f16
//  - moving W pointers, 4 loads with immediate offsets (0/1024/2048/3072 B)
//  - moving xj LDS bases, ds_read immediate offsets (0/64/8192/8256 B)
//  - last-pair prefetch skipped via uniform branch (no clamped reload)

typedef _Float16 f16;
typedef __attribute__((ext_vector_type(8))) _Float16 half8;
typedef __attribute__((ext_vector_type(2))) _Float16 half2v;
typedef __attribute__((ext_vector_type(16))) float f32x16;
typedef __attribute__((ext_vector_type(4))) float f32x4;

#define MFMA(a, b, c) __builtin_amdgcn_mfma_f32_32x32x16_f16(a, b, c, 0, 0, 0)

union H8 { half8 v; half2v h[4]; };

__device__ __forceinline__ half8 scale8(half8 a, half2v hh) {
  H8 in, out;
  in.v = a;
  out.h[0] = in.h[0] * hh;
  out.h[1] = in.h[1] * hh;
  out.h[2] = in.h[2] * hh;
  out.h[3] = in.h[3] * hh;
  return out.v;
}

// ---- pre-pass: scatter W f32 -> f16 fragment-major ----
// Wb slot layout: [c][slot][8], slot = (g*4+kk)*64 + hi*32 + lr
//   holds W[f=g*32+lr][c][kk*16+hi*8 .. +8]
__global__ __launch_bounds__(256) void wscat_kernel(const float* __restrict__ W,
                                                    f16* __restrict__ Wb) {
  const int tid = blockIdx.x * 256 + threadIdx.x;   // 65536 threads
  const int c = tid >> 10, s = tid & 1023;
  const int gk = s >> 6, ln = s & 63;
  const int g = gk >> 2, kk = gk & 3, hi = ln >> 5, lr = ln & 31;
  const int f = g * 32 + lr, n0 = kk * 16 + hi * 8;
  const float* src = W + (size_t)f * 4096 + c * 64 + n0;
  const float4 a = *(const float4*)src;
  const float4 b = *(const float4*)(src + 4);
  half8 r;
  r[0] = (f16)a.x; r[1] = (f16)a.y; r[2] = (f16)a.z; r[3] = (f16)a.w;
  r[4] = (f16)b.x; r[5] = (f16)b.y; r[6] = (f16)b.z; r[7] = (f16)b.w;
  *(half8*)(Wb + (size_t)c * 8192 + s * 8) = r;
}

__global__ __launch_bounds__(256, 2) void cin_kernel(
    const float* __restrict__ xj, const float* __restrict__ x0,
    const f16* __restrict__ Wb, float* __restrict__ out,
    float* __restrict__ pout) {
  // x0T[bb*4096 + d*64 + ((n>>3)^(d&7))*8 + (n&7)] = f16(x0[b0+bb][n][d])
  __shared__ f16 x0T[2 * 4096];   // 16 KB
  // xjL[bb*4096 + c*64 + d] = f16(xj[b0+bb][c][d])   (linear copy)
  __shared__ f16 xjL[2 * 4096];   // 16 KB

  const int t = threadIdx.x;
  const int wid = t >> 6, lane = t & 63;
  const int b0 = blockIdx.x * 2;

  // ---- one-time: stage x0 (transposed, swizzled) + xj (linear) as f16 ----
#pragma unroll
  for (int bb = 0; bb < 2; ++bb) {
    const float* s0 = x0 + (size_t)(b0 + bb) * 4096;
    const float* sj = xj + (size_t)(b0 + bb) * 4096;
    {
      const int n = lane, d0 = wid * 16;
      const int chb = n >> 3, sub = n & 7;
#pragma unroll
      for (int q = 0; q < 4; ++q) {
        const float4 v = *(const float4*)(s0 + n * 64 + d0 + q * 4);
#pragma unroll
        for (int j = 0; j < 4; ++j) {
          const int d = d0 + q * 4 + j;
          x0T[bb * 4096 + d * 64 + ((chb ^ (d & 7)) << 3) + sub] =
              (f16)(((const float*)&v)[j]);
        }
      }
    }
#pragma unroll
    for (int p = 0; p < 4; ++p) {
      const int e = p * 1024 + t * 4;
      const float4 v = *(const float4*)(sj + e);
      f16* dst = &xjL[bb * 4096 + e];
      dst[0] = (f16)v.x; dst[1] = (f16)v.y; dst[2] = (f16)v.z; dst[3] = (f16)v.w;
    }
  }
  __syncthreads();

  const int wg = wid;                       // f-group: f = wg*32 + lr
  const int lr = lane & 31, hi = lane >> 5;

  // ---- hoisted x0 A-fragments: af[mf][kk], mf = (bb<<1)|dh ----
  half8 af[4][4];
#pragma unroll
  for (int mf = 0; mf < 4; ++mf) {
    const int bb = mf >> 1;
    const int d = (mf & 1) * 32 + lr;
#pragma unroll
    for (int kk = 0; kk < 4; ++kk)
      af[mf][kk] = *(const half8*)&x0T[bb * 4096 + d * 64 +
                                       (((kk * 2 + hi) ^ (d & 7)) << 3)];
  }

  f32x16 acc[4] = {};

  // W stream: wave wg's slice, 16B/lane contiguous per (c,kk)
  const half8* wp = (const half8*)Wb + wg * 256 + lane;   // + c*1024 + kk*64
  // xj LDS read bases (element units); offsets {0,32,4096,4128} -> ds imm
  const f16* xjA = &xjL[lr];          // even c
  const f16* xjB = &xjL[lr] + 64;     // odd c

  // ---- prologue: c=0 -> A sets, c=1 -> B sets ----
  half8 wA0 = wp[0],    wA1 = wp[64],        wA2 = wp[128],        wA3 = wp[192];
  half8 wB0 = wp[1024], wB1 = wp[1024 + 64], wB2 = wp[1024 + 128], wB3 = wp[1024 + 192];
  f16 xA0 = xjA[0], xA1 = xjA[32], xA2 = xjA[4096], xA3 = xjA[4096 + 32];
  f16 xB0 = xjB[0], xB1 = xjB[32], xB2 = xjB[4096], xB3 = xjB[4096 + 32];

  // moving prefetch pointers (next targets: c=2 / c=3)
  const half8* wpA = wp + 2048;
  const half8* wpB = wp + 3072;
  const f16* xjpA = xjA + 128;
  const f16* xjpB = xjB + 128;

#pragma unroll 1
  for (int cc = 0; cc < 32; ++cc) {
    // ================= even c = 2*cc (A sets) =================
    {
      const half2v h0 = {xA0, xA0}, h1 = {xA1, xA1}, h2 = {xA2, xA2}, h3 = {xA3, xA3};
      __builtin_amdgcn_s_setprio(1);
#pragma unroll
      for (int kk = 0; kk < 4; ++kk) {
        const half8 w = (kk == 0) ? wA0 : (kk == 1) ? wA1 : (kk == 2) ? wA2 : wA3;
        acc[0] = MFMA(scale8(af[0][kk], h0), w, acc[0]);
        acc[1] = MFMA(scale8(af[1][kk], h1), w, acc[1]);
        acc[2] = MFMA(scale8(af[2][kk], h2), w, acc[2]);
        acc[3] = MFMA(scale8(af[3][kk], h3), w, acc[3]);
      }
      __builtin_amdgcn_s_setprio(0);
      if (cc < 31) {
        wA0 = wpA[0]; wA1 = wpA[64]; wA2 = wpA[128]; wA3 = wpA[192];
        xA0 = xjpA[0]; xA1 = xjpA[32]; xA2 = xjpA[4096]; xA3 = xjpA[4096 + 32];
        wpA += 2048; xjpA += 128;
      }
    }
    // ================= odd c = 2*cc+1 (B sets) =================
    {
      const half2v h0 = {xB0, xB0}, h1 = {xB1, xB1}, h2 = {xB2, xB2}, h3 = {xB3, xB3};
      __builtin_amdgcn_s_setprio(1);
#pragma unroll
      for (int kk = 0; kk < 4; ++kk) {
        const half8 w = (kk == 0) ? wB0 : (kk == 1) ? wB1 : (kk == 2) ? wB2 : wB3;
        acc[0] = MFMA(scale8(af[0][kk], h0), w, acc[0]);
        acc[1] = MFMA(scale8(af[1][kk], h1), w, acc[1]);
        acc[2] = MFMA(scale8(af[2][kk], h2), w, acc[2]);
        acc[3] = MFMA(scale8(af[3][kk], h3), w, acc[3]);
      }
      __builtin_amdgcn_s_setprio(0);
      if (cc < 31) {
        wB0 = wpB[0]; wB1 = wpB[64]; wB2 = wpB[128]; wB3 = wpB[192];
        xB0 = xjpB[0]; xB1 = xjpB[32]; xB2 = xjpB[4096]; xB3 = xjpB[4096 + 32];
        wpB += 2048; xjpB += 128;
      }
    }
  }

  // ---- epilogue: D layout col=lane&31 (f), row=(reg&3)+8*(reg>>2)+4*hi (d) ----
  const int fcol = wg * 32 + lr;
  float ps[4];
#pragma unroll
  for (int mf = 0; mf < 4; ++mf) {
    const int b = b0 + (mf >> 1);
    float* ob = out + (size_t)b * 8192 + (size_t)fcol * 64 + (mf & 1) * 32;
    const f32x16 v = acc[mf];
    float s = 0.f;
#pragma unroll
    for (int q = 0; q < 4; ++q) {
      f32x4 vv = { v[4 * q], v[4 * q + 1], v[4 * q + 2], v[4 * q + 3] };
      *(f32x4*)(ob + q * 8 + hi * 4) = vv;
      s += vv[0] + vv[1] + vv[2] + vv[3];
    }
    ps[mf] = s;
  }
  float pA = ps[0] + ps[1];   // batch b0
  float pB = ps[2] + ps[3];   // batch b0+1
  pA += __shfl_xor(pA, 32, 64);
  pB += __shfl_xor(pB, 32, 64);
  if (hi == 0) {
    pout[(size_t)b0 * 128 + fcol] = pA;
    pout[(size_t)(b0 + 1) * 128 + fcol] = pB;
  }
}

extern "C" void kernel_launch(void* const* d_in, const int* in_sizes, int n_in,
                              void* d_out, int out_size, void* d_ws, size_t ws_size,
                              hipStream_t stream) {
  const float* xj = (const float*)d_in[0];   // (2048, 64, 64)
  const float* x0 = (const float*)d_in[1];   // (2048, 64, 64)
  const float* W  = (const float*)d_in[2];   // (128, 64, 64)
  float* out  = (float*)d_out;               // cin_out (2048,128,64), cin_p_out (2048,128)
  float* pout = out + (size_t)2048 * 128 * 64;
  f16* Wb = (f16*)d_ws;                      // 1 MiB fragment-major f16 W

  wscat_kernel<<<256, 256, 0, stream>>>(W, Wb);
  cin_kernel<<<1024, 256, 0, stream>>>(xj, x0, Wb, out, pout);
}